// Round 3
// baseline (796.021 us; speedup 1.0000x reference)
//
#include <hip/hip_runtime.h>

// PRNNLayer: B=4096 chains x T=2048 sequential steps, 5 states.
// R3: role-split — 4 waves per 64-chain block, each wave owns a subset of the
// 5 (nearly independent) state recurrences. The only cross-state values
// (w = prain+melt, pe) flow s1-wave -> s3-wave through a double-buffered LDS
// ring with the producer one 16-step chunk ahead: 1 barrier per 16 steps.
// Raw s_barrier (lgkmcnt only) keeps global prefetches in flight across it.

#define NT 2048
#define CH 16
#define NC (NT / CH)          // 128 chunks

#define L2E10 14.4269504089f  // 10*log2(e)
#define L2E    1.44269504089f

__device__ __forceinline__ float rcpf(float x) { return __builtin_amdgcn_rcpf(x); }
__device__ __forceinline__ float ex2(float a)  { return __builtin_amdgcn_exp2f(a); }
__device__ __forceinline__ float ex2c(float a) { return __builtin_amdgcn_exp2f(fminf(a, 80.0f)); }
__device__ __forceinline__ float clip1e5(float x) {
    return __builtin_amdgcn_fmed3f(x, -100000.0f, 100000.0f);
}
// Barrier that waits only LDS ops (lgkmcnt), NOT vmcnt: global prefetch loads
// stay in flight across it (unlike __syncthreads which drains vmcnt(0)).
__device__ __forceinline__ void wg_barrier() {
    asm volatile("s_waitcnt lgkmcnt(0)\n\ts_barrier" ::: "memory");
}

__global__ __launch_bounds__(256, 1)
void prnn_kernel(const float* __restrict__ inp, const float* __restrict__ theta,
                 float* __restrict__ out)
{
    const int role = threadIdx.x >> 6;   // wave index in block = role (uniform)
    const int lane = threadIdx.x & 63;
    const int b    = blockIdx.x * 64 + lane;

    __shared__ float2 xbuf[2][CH][64];   // [slot][t][chain] = (prain+melt, pe)

    // ---- theta (uniform -> SGPRs), constant-folded ----
    const float f_     = theta[0] * 0.1f;
    const float smax_  = theta[1] * 1950.0f;
    const float qmax_  = theta[2] * 50.0f;
    const float ddf_   = theta[3] * 5.0f;
    const float tmin_  = theta[4] * -3.0f;
    const float tmax_  = theta[5] * 3.0f;
    const float Kc_    = theta[6] * 0.5f;
    const float SCmax_ = theta[7] * 1.5f;
    const float spmax_ = theta[8] * 1950.0f;
    const float qpmax_ = theta[9] * 40.0f;
    const float kp     = theta[10];
    const float sgmax_ = theta[11] * 1950.0f;
    const float qgmax_ = theta[12] * 40.0f;
    const float Kl_    = theta[13] * 0.5f;
    const float Kn_    = theta[14] * 0.5f;

    const float inv_smax = rcpf(smax_);
    const float KcDc  = Kc_ * 0.849932f;         // Kc_ * 0.986 * 0.862
    const float c_sn  = -L2E10 * tmin_;
    const float c_m   =  L2E10 * tmax_;
    const float c_dd  = -ddf_ * tmax_;
    const float c_sc1 =  L2E10 * SCmax_ * 1.4f;
    const float c_sc0 =  L2E10 * SCmax_ * 0.6f;
    const float c_2p  =  L2E10 * spmax_;
    const float c_3s  =  L2E10 * smax_;
    const float c_4s  =  L2E10 * sgmax_;
    const float fE    = f_ * L2E;
    const float c_E2  = -fE * spmax_;
    const float c_E3  = -fE * smax_;
    const float c_E4  = -fE * sgmax_;

    const float* ip = inp + (size_t)b * (NT * 3);
    float*       op = out + (size_t)b * (NT * 5);

    float s   = 0.0f;   // this role's primary state (s0 / s1 / s2 / s3)
    float s4v = 0.0f;   // role 2's second state (s4)

    float bufA[CH * 3];
    float bufB[CH * 3];

    auto prefetch = [&](float* dst, int c) {
        const float4* src = (const float4*)(ip + (size_t)c * (CH * 3));
        float4* d4 = (float4*)dst;
        #pragma unroll
        for (int i = 0; i < (CH * 3) / 4; ++i) d4[i] = src[i];
    };

    // role 1 computes chunk `it` at iteration `it` (producer, lag 0);
    // roles 0/2/3 compute chunk `it-1` (lag 1). One barrier per iteration.
    const int lag = (role == 1) ? 0 : 1;

    auto step_iter = [&](int it, float* rd, float* wr) {
        const int mc = it - lag;          // chunk computed this iteration
        const int pc = mc + 1;            // chunk prefetched this iteration
        if (role != 3 && pc >= 0 && pc < NC) prefetch(wr, pc);
        if (mc >= 0 && mc < NC) {
            float* o = op + (size_t)(mc * CH) * 5;
            if (role == 0) {
                #pragma unroll
                for (int t = 0; t < CH; ++t) {
                    const float p  = rd[t * 3 + 0];
                    const float dl = rd[t * 3 + 2];
                    const float day = rcpf(1.0f + ex2(fmaf(-L2E10, dl, 7.2134752f)));
                    const float lai = fmaf(0.328f, day, 0.15f);
                    const float kcf = fmaf(0.6f, day, 0.4f);
                    const float kterm = KcDc * kcf * lai;
                    const float ea  = ex2(fmaf(-L2E10, p, L2E));
                    const float e0  = ex2(-L2E10 * s);
                    const float esc = ex2c(fmaf(c_sc1, day, fmaf(-L2E10, s, c_sc0)));
                    const float d0  = 1.0f + e0;
                    const float Rp  = rcpf((1.0f + ea) * d0 * (1.0f + esc));
                    const float pintc = Rp * fmaf(d0 * esc, kterm, p);
                    s += clip1e5(pintc);
                    o[t * 5 + 0] = s;
                }
            } else if (role == 1) {
                const int sl = mc & 1;
                #pragma unroll
                for (int t = 0; t < CH; ++t) {
                    const float p  = rd[t * 3 + 0];
                    const float tm = rd[t * 3 + 1];
                    const float dl = rd[t * 3 + 2];
                    const float psnow = rcpf(1.0f + ex2(fmaf(L2E10, tm, c_sn))) * p;
                    const float em = ex2(fmaf(-L2E10, tm, c_m));
                    const float e1 = ex2(-L2E10 * s);
                    const float melt = rcpf((1.0f + em) * (1.0f + e1))
                                       * fminf(s, fmaf(ddf_, tm, c_dd));
                    const float A1 = tm + 237.3f;
                    const float A2 = tm + 273.2f;
                    const float q  = rcpf(A1 * A2);
                    const float pe = 436.9872f * dl
                                     * ex2(24.9586242f * tm * (q * A2)) * (q * A1);
                    xbuf[sl][t][lane] = make_float2((p - psnow) + melt, pe);
                    s += clip1e5(psnow - melt);
                    o[t * 5 + 1] = s;
                }
            } else if (role == 2) {
                #pragma unroll
                for (int t = 0; t < CH; ++t) {
                    const float p = rd[t * 3 + 0];
                    const float e2  = ex2(-L2E10 * s);
                    const float e2p = ex2c(fmaf(-L2E10, s, c_2p));
                    const float E2  = ex2(fmaf(fE, s, c_E2));
                    const float R2f = rcpf((1.0f + e2) * (1.0f + e2p));
                    const float qpref = R2f * fmaf(e2p * E2, kp * p, qpmax_);
                    s += clip1e5(qpref);
                    o[t * 5 + 2] = s;
                    const float e4  = ex2(-L2E10 * s4v);
                    const float e4s = ex2c(fmaf(-L2E10, s4v, c_4s));
                    const float E4  = ex2(fmaf(fE, s4v, c_E4));
                    const float R4f = rcpf((1.0f + e4) * (1.0f + e4s));
                    const float pl  = p * fmaf(p, Kn_, Kl_);
                    const float qslow = R4f * fmaf(e4s * E4, pl, qgmax_);
                    s4v += clip1e5(qslow);
                    o[t * 5 + 4] = s4v;
                }
            } else {
                const int sl = mc & 1;
                #pragma unroll
                for (int t = 0; t < CH; ++t) {
                    const float2 wp = xbuf[sl][t][lane];   // (prain+melt, pe)
                    const float e3  = ex2(-L2E10 * s);
                    const float e3s = ex2c(fmaf(-L2E10, s, c_3s));
                    const float E3  = ex2(fmaf(fE, s, c_E3));
                    const float R3  = rcpf((1.0f + e3) * (1.0f + e3s));
                    const float t_et = wp.y * fmaf(e3s * s, inv_smax, 1.0f);
                    const float t_qs = qmax_ * fmaf(e3s, E3, 1.0f);
                    const float outflux = R3 * (t_et + t_qs + (s - smax_));
                    s += clip1e5(wp.x - outflux);
                    o[t * 5 + 3] = s;
                }
            }
        }
    };

    if (role == 1) prefetch(bufA, 0);   // producer's first chunk

    // NC+1 productive iterations; loop does NC+2 (even count) — the final
    // iteration computes/prefetches nothing, just a barrier (harmless).
    for (int it = 0; it < NC + 2; it += 2) {
        step_iter(it,     bufA, bufB);
        wg_barrier();
        step_iter(it + 1, bufB, bufA);
        wg_barrier();
    }
}

extern "C" void kernel_launch(void* const* d_in, const int* in_sizes, int n_in,
                              void* d_out, int out_size, void* d_ws, size_t ws_size,
                              hipStream_t stream) {
    const float* inp   = (const float*)d_in[0];
    const float* theta = (const float*)d_in[1];
    float* out = (float*)d_out;
    prnn_kernel<<<4096 / 64, 256, 0, stream>>>(inp, theta, out);
}